// Round 3
// baseline (379.779 us; speedup 1.0000x reference)
//
#include <hip/hip_runtime.h>
#include <math.h>

// B=4, S=1024, D=768, H=12, E=64, 3D=2304
// Workspace layout (bytes), total ~137 MB:
//   scbuf fp16 final probs P2 [b][q][g][k] head-minor : 100,663,296 @ 0
//   qkf  fp16 [4096][1536] (Q,K)  : 12,582,912 @ 100,663,296
//   vbuf fp16 [4096][768]  (V)    :  6,291,456 @ 113,246,208
//   ctx  fp16 [4096][768]         :  6,291,456 @ 119,537,664   (reused as dpart before k_pv)
//   x_h  fp16 :  6,291,456 @ 125,829,120                       (reused as dfinal after k_qkv)
//   wq_h fp16 :  3,538,944 @ 132,120,576
//   wp_h fp16 :  1,179,648 @ 135,659,520
//
// Two-pass fused scores (no S round-trip). R3 schedule fix vs R2:
//  - one staging phase + one barrier pair per block (was 24 barrier pairs)
//  - K tile staged as contiguous rows w/ source-XOR swizzle; Q read L2->VGPR
//  - conflict-free Tout repack (quad-XOR chunk swizzle), exact 48KB alias of K

typedef _Float16 f16;
typedef __attribute__((ext_vector_type(8))) _Float16 f16x8;
typedef __attribute__((ext_vector_type(4))) float f32x4;
typedef unsigned short u16;

__device__ __forceinline__ u16 f2h(float f) {
  f16 h = (f16)f;
  return __builtin_bit_cast(u16, h);
}

__device__ __forceinline__ void async16(const void* g, void* l) {
  __builtin_amdgcn_global_load_lds(
      (const __attribute__((address_space(1))) unsigned int*)g,
      (__attribute__((address_space(3))) unsigned int*)l, 16, 0, 0);
}

#define MFMA_F16(a, b, c) __builtin_amdgcn_mfma_f32_16x16x32_f16((a), (b), (c), 0, 0, 0)

// ---------------- prep: cast x, Wqkv, Wp to fp16 ----------------
__global__ __launch_bounds__(256) void k_prep(const float* __restrict__ x,
                                              const float* __restrict__ Wqkv,
                                              const float* __restrict__ Wp,
                                              u16* __restrict__ xh,
                                              u16* __restrict__ wh,
                                              u16* __restrict__ wph) {
  const int blk = blockIdx.x, t = threadIdx.x;
  if (blk < 3072) {
    int i = blk * 256 + t;
    float4 v = ((const float4*)x)[i];
    ((ushort4*)xh)[i] = make_ushort4(f2h(v.x), f2h(v.y), f2h(v.z), f2h(v.w));
  } else if (blk < 4800) {
    int i = (blk - 3072) * 256 + t;
    float4 v = ((const float4*)Wqkv)[i];
    ((ushort4*)wh)[i] = make_ushort4(f2h(v.x), f2h(v.y), f2h(v.z), f2h(v.w));
  } else {
    int i = (blk - 4800) * 256 + t;
    float4 v = ((const float4*)Wp)[i];
    ((ushort4*)wph)[i] = make_ushort4(f2h(v.x), f2h(v.y), f2h(v.z), f2h(v.w));
  }
}

// ---------------- K1: qkv = x @ Wqkv^T, fp16 single-MFMA ----------------
__global__ __launch_bounds__(256) void k_qkv(const u16* __restrict__ Axh,
                                             const u16* __restrict__ Bwh,
                                             u16* __restrict__ qkf,
                                             u16* __restrict__ vbuf) {
  __shared__ u16 smem[16384];
  u16* As = smem;
  u16* Bs = smem + 4096;
  const int t = threadIdx.x, lane = t & 63, wave = t >> 6;
  const int wm = wave >> 1, wn = wave & 1;
  const int quad = lane >> 4, l16 = lane & 15;
  const int pid = blockIdx.x;
  const int group = pid / 144;
  const int rem = pid - group * 144;
  const int m0 = (group * 8 + (rem & 7)) * 128;
  const int n0 = (rem >> 3) * 128;
  const bool vblk = (n0 >= 1536);
  const int srow = t >> 2, sch = (t & 3) * 8;
  f32x4 acc[4][4];
#pragma unroll
  for (int i = 0; i < 4; ++i)
#pragma unroll
    for (int j = 0; j < 4; ++j) acc[i][j] = (f32x4){0.f, 0.f, 0.f, 0.f};
  for (int k0 = 0; k0 < 768; k0 += 32) {
    const size_t ga = (size_t)(m0 + srow) * 768 + k0 + sch;
    const size_t gb = (size_t)(n0 + srow) * 768 + k0 + sch;
    __syncthreads();
    async16(Axh + ga, &As[t * 8]);
    async16(Axh + ga + (size_t)64 * 768, &As[2048 + t * 8]);
    async16(Bwh + gb, &Bs[t * 8]);
    async16(Bwh + gb + (size_t)64 * 768, &Bs[2048 + t * 8]);
    __syncthreads();
    f16x8 af[4], bfr[4];
#pragma unroll
    for (int i = 0; i < 4; ++i) af[i] = *(const f16x8*)&As[(wm * 64 + i * 16 + l16) * 32 + quad * 8];
#pragma unroll
    for (int j = 0; j < 4; ++j) bfr[j] = *(const f16x8*)&Bs[(wn * 64 + j * 16 + l16) * 32 + quad * 8];
#pragma unroll
    for (int i = 0; i < 4; ++i)
#pragma unroll
      for (int j = 0; j < 4; ++j) acc[i][j] = MFMA_F16(af[i], bfr[j], acc[i][j]);
  }
  __syncthreads();
  u16* T = smem;
#pragma unroll
  for (int i = 0; i < 4; ++i)
#pragma unroll
    for (int j = 0; j < 4; ++j)
#pragma unroll
      for (int r = 0; r < 4; ++r) {
        const int row = wm * 64 + i * 16 + quad * 4 + r;
        const int col = wn * 64 + j * 16 + l16;
        T[row * 128 + (col ^ ((row & 7) << 4))] = f2h(acc[i][j][r]);
      }
  __syncthreads();
  const int row = t >> 1, halfc = (t & 1) * 64;
  const int sw = (row & 7) << 4;
  u16* dst = vblk ? (vbuf + (size_t)(m0 + row) * 768 + (n0 - 1536) + halfc)
                  : (qkf + (size_t)(m0 + row) * 1536 + n0 + halfc);
#pragma unroll
  for (int c = 0; c < 64; c += 8)
    *(uint4*)(dst + c) = *(const uint4*)&T[row * 128 + ((halfc + c) ^ sw)];
}

// ---------------- shared: all-heads QK tile, 64q x 32k, 12 heads ----------------
// Waves 2(m over 64q: 32 each, 2 i-frags) x 2(n over 32k: 16 each).
// acc[h][i]: C rows = wm*32 + i*16 + quad*4 + r, cols = wn*16 + l16.
// K tile (32 rows x 768 feats = 48KB) staged once, source-XOR-swizzled.
// Q frags loaded global->VGPR inside the (barrier-free) head loop.
__device__ __forceinline__ void qk_heads2(const u16* __restrict__ qkf,
                                          int b, int q0, int k0, int t,
                                          u16* Ks, f32x4 (&acc)[12][2]) {
  const int lane = t & 63, wave = t >> 6;
  const int wm = wave >> 1, wn = wave & 1;
  const int quad = lane >> 4, l16 = lane & 15;
#pragma unroll
  for (int h = 0; h < 12; ++h)
#pragma unroll
    for (int i = 0; i < 2; ++i) acc[h][i] = (f32x4){0.f, 0.f, 0.f, 0.f};
  // stage K: 32 rows x 96 16B-chunks; chunk low3 XOR'ed with row&7 on the SOURCE
#pragma unroll
  for (int i = 0; i < 12; ++i) {
    const int idx = i * 256 + t;
    const int row = idx / 96, c = idx - row * 96;
    const int cs = (c & ~7) | ((c ^ row) & 7);
    async16(qkf + (size_t)(b * 1024 + k0 + row) * 1536 + 768 + cs * 8, &Ks[idx * 8]);
  }
  const u16* qrow = qkf + (size_t)(b * 1024 + q0 + wm * 32 + l16) * 1536;
  const int r0 = wn * 16 + l16;
  const int rx = r0 & 7;
  __syncthreads();
#pragma unroll
  for (int h = 0; h < 12; ++h) {
    f16x8 a00 = *(const f16x8*)(qrow + h * 64 + quad * 8);
    f16x8 a01 = *(const f16x8*)(qrow + h * 64 + 32 + quad * 8);
    f16x8 a10 = *(const f16x8*)(qrow + 16 * 1536 + h * 64 + quad * 8);
    f16x8 a11 = *(const f16x8*)(qrow + 16 * 1536 + h * 64 + 32 + quad * 8);
    f16x8 b0 = *(const f16x8*)&Ks[r0 * 768 + (h * 8 + ((quad ^ rx) & 7)) * 8];
    f16x8 b1 = *(const f16x8*)&Ks[r0 * 768 + (h * 8 + (((4 + quad) ^ rx) & 7)) * 8];
    acc[h][0] = MFMA_F16(a00, b0, acc[h][0]);
    acc[h][0] = MFMA_F16(a01, b1, acc[h][0]);
    acc[h][1] = MFMA_F16(a10, b0, acc[h][1]);
    acc[h][1] = MFMA_F16(a11, b1, acc[h][1]);
  }
}

__device__ __forceinline__ void mix1_g(const f32x4 (&acc)[12][2], const float* wl_s,
                                       float b0, int g, f32x4& L0, f32x4& L1) {
  L0 = (f32x4){b0, b0, b0, b0};
  L1 = L0;
#pragma unroll
  for (int h = 0; h < 12; ++h) {
    const float w = wl_s[g * 12 + h];
    const f32x4 wv = {w, w, w, w};
    L0 = __builtin_elementwise_fma(wv, acc[h][0], L0);
    L1 = __builtin_elementwise_fma(wv, acc[h][1], L1);
  }
}

// ---------------- passA: QK + mix1 + exp -> partial row sums ----------------
// grid (kt=32, qt=16, b=4). dpart[(b*16+qt)*32+kt][row*12+g] f32, row in [0,64).
__global__ __launch_bounds__(256) void k_qkmix_sum(const u16* __restrict__ qkf,
                                                   const float* __restrict__ Wl,
                                                   const float* __restrict__ bl,
                                                   float* __restrict__ dpart) {
  __shared__ u16 Ks[24576];            // 48KB
  __shared__ float wl_s[144], bl_s[12];
  __shared__ float dred[2][768];
  const int t = threadIdx.x;
  if (t < 144) wl_s[t] = Wl[t];
  if (t < 12) bl_s[t] = bl[t];
  const int kt = blockIdx.x, qt = blockIdx.y, b = blockIdx.z;
  const int lane = t & 63, wave = t >> 6;
  const int wm = wave >> 1, wn = wave & 1;
  const int quad = lane >> 4, l16 = lane & 15;
  f32x4 acc[12][2];
  qk_heads2(qkf, b, qt * 64, kt * 32, t, Ks, acc);   // internal barrier covers wl_s too
#pragma unroll
  for (int g = 0; g < 12; ++g) {
    f32x4 L0, L1;
    mix1_g(acc, wl_s, bl_s[g] - 16.f, g, L0, L1);
    f32x4 e0, e1;
#pragma unroll
    for (int r = 0; r < 4; ++r) { e0[r] = __expf(L0[r]); e1[r] = __expf(L1[r]); }
    // reduce over this wave's 16 k-cols (l16 lanes)
#pragma unroll
    for (int m = 1; m <= 8; m <<= 1) {
#pragma unroll
      for (int r = 0; r < 4; ++r) {
        e0[r] += __shfl_xor(e0[r], m);
        e1[r] += __shfl_xor(e1[r], m);
      }
    }
    if (l16 == 0) {
#pragma unroll
      for (int r = 0; r < 4; ++r) {
        dred[wn][(wm * 32 + 0 * 16 + quad * 4 + r) * 12 + g] = e0[r];
        dred[wn][(wm * 32 + 1 * 16 + quad * 4 + r) * 12 + g] = e1[r];
      }
    }
  }
  __syncthreads();
  const size_t base = (size_t)((b * 16 + qt) * 32 + kt) * 768;
  for (int s = t; s < 768; s += 256) dpart[base + s] = dred[0][s] + dred[1][s];
}

// ---------------- k_dsum: reduce partials over kt, invert ----------------
__global__ __launch_bounds__(256) void k_dsum(const float* __restrict__ dpart,
                                              float* __restrict__ dfinal) {
  const int blk = blockIdx.x;
  const int bq = blk / 3, part = blk % 3;
  const int slot = part * 256 + threadIdx.x;
  const float* p = dpart + (size_t)bq * 24576 + slot;
  float s = 0.f;
#pragma unroll
  for (int kt = 0; kt < 32; ++kt) s += p[kt * 768];
  dfinal[(size_t)bq * 768 + slot] = 1.0f / s;
}

// ---------------- passB: QK + mix1 + exp*dinv + mix2 -> store P2 ----------------
// grid (kt=32, qt=16, b=4). Output scbuf [b][q][g][k] head-minor.
__global__ __launch_bounds__(256) void k_qkmix_store(const u16* __restrict__ qkf,
                                                     const float* __restrict__ Wl,
                                                     const float* __restrict__ bl,
                                                     const float* __restrict__ Ww,
                                                     const float* __restrict__ bw,
                                                     const float* __restrict__ dfinal,
                                                     u16* __restrict__ scbuf) {
  __shared__ u16 Ks[24576];            // 48KB; reused as Tout[64q][12g][4 chunks][8]
  __shared__ float wl_s[144], ww_s[144], bl_s[12], bw_s[12];
  __shared__ float dinv_s[768];
  const int t = threadIdx.x;
  if (t < 144) { wl_s[t] = Wl[t]; ww_s[t] = Ww[t]; }
  if (t < 12)  { bl_s[t] = bl[t]; bw_s[t] = bw[t]; }
  const int kt = blockIdx.x, qt = blockIdx.y, b = blockIdx.z;
  const int q0 = qt * 64, k0 = kt * 32;
  {
    const size_t dbase = (size_t)(b * 16 + qt) * 768;
    for (int s = t; s < 768; s += 256) dinv_s[s] = dfinal[dbase + s];
  }
  const int lane = t & 63, wave = t >> 6;
  const int wm = wave >> 1, wn = wave & 1;
  const int quad = lane >> 4, l16 = lane & 15;
  f32x4 acc[12][2];
  qk_heads2(qkf, b, q0, k0, t, Ks, acc);   // internal barrier covers smem inits
  // O[g2][i] accumulates mix2 on the fly (avoids acc+P both at 96 regs)
  f32x4 O[12][2];
#pragma unroll
  for (int g2 = 0; g2 < 12; ++g2) {
    O[g2][0] = (f32x4){bw_s[g2], bw_s[g2], bw_s[g2], bw_s[g2]};
    O[g2][1] = O[g2][0];
  }
#pragma unroll
  for (int g = 0; g < 12; ++g) {
    f32x4 L0, L1;
    mix1_g(acc, wl_s, bl_s[g] - 16.f, g, L0, L1);
    f32x4 P0, P1;
#pragma unroll
    for (int r = 0; r < 4; ++r) {
      const int rw0 = wm * 32 + quad * 4 + r;
      P0[r] = __expf(L0[r]) * dinv_s[rw0 * 12 + g];
      P1[r] = __expf(L1[r]) * dinv_s[(rw0 + 16) * 12 + g];
    }
#pragma unroll
    for (int g2 = 0; g2 < 12; ++g2) {
      const float w = ww_s[g2 * 12 + g];
      const f32x4 wv = {w, w, w, w};
      O[g2][0] = __builtin_elementwise_fma(wv, P0, O[g2][0]);
      O[g2][1] = __builtin_elementwise_fma(wv, P1, O[g2][1]);
    }
  }
  // Tout repack in Ks region (K dead). Layout: [(q*12+g)][4 chunks of 8 u16],
  // chunk slot XOR'ed with quad bits of q ((row>>2)&3) -> conflict-free.
  __syncthreads();
  u16* Tout = Ks;
  const int chunkbase = wn * 2 + (l16 >> 3);   // col = wn*16+l16 -> chunk, within
  const int cw = l16 & 7;
#pragma unroll
  for (int g2 = 0; g2 < 12; ++g2)
#pragma unroll
    for (int i = 0; i < 2; ++i)
#pragma unroll
      for (int r = 0; r < 4; ++r) {
        const int row = wm * 32 + i * 16 + quad * 4 + r;
        const int slot = chunkbase ^ quad;     // (row>>2)&3 == quad
        Tout[(row * 12 + g2) * 32 + slot * 8 + cw] = f2h(O[g2][i][r]);
      }
  __syncthreads();
  // coalesced 16B stores: 3072 chunks, 12 per thread
#pragma unroll
  for (int i = 0; i < 12; ++i) {
    const int ci = i * 256 + t;
    const int q = ci / 48, rem = ci - q * 48;
    const int g = rem >> 2, chunk = rem & 3;
    const int slot = chunk ^ ((q >> 2) & 3);
    uint4 v = *(const uint4*)&Tout[(q * 12 + g) * 32 + slot * 8];
    *(uint4*)(scbuf + ((size_t)(b * 1024 + q0 + q) * 12 + g) * 1024 + k0 + chunk * 8) = v;
  }
}

// ---------------- K4: ctx = P2(fp16) @ V(fp16) per (b,h) ----------------
__global__ __launch_bounds__(256) void k_pv(const u16* __restrict__ probs,
                                            const u16* __restrict__ vbuf,
                                            u16* __restrict__ ctx) {
  __shared__ u16 As[4096];
  __shared__ u16 Bs[64 * 40];
  const int t = threadIdx.x, lane = t & 63, wave = t >> 6;
  const int wm = wave >> 1, wn = wave & 1;
  const int quad = lane >> 4, l16 = lane & 15;
  const int bh = blockIdx.y, b = bh / 12, h = bh % 12;
  const int m0 = blockIdx.x * 128;
  const int srow = t >> 2, sch = (t & 3) * 8;
  const int ev = t & 63, s8 = (t >> 6) * 8;
  f32x4 acc[4][2];
#pragma unroll
  for (int i = 0; i < 4; ++i)
#pragma unroll
    for (int j = 0; j < 2; ++j) acc[i][j] = (f32x4){0.f, 0.f, 0.f, 0.f};
  for (int k0 = 0; k0 < 1024; k0 += 32) {
    const u16* vp = vbuf + (size_t)(b * 1024 + k0 + s8) * 768 + h * 64 + ev;
    u16 vcol[8];
#pragma unroll
    for (int i = 0; i < 8; ++i) vcol[i] = vp[(size_t)i * 768];
    __syncthreads();
    const u16* ga = probs + ((size_t)(b * 1024 + m0 + srow) * 12 + h) * 1024 + k0 + sch;
    async16(ga, &As[t * 8]);
    async16(ga + (size_t)64 * 12 * 1024, &As[2048 + t * 8]);
    *(ushort4*)&Bs[ev * 40 + s8] = make_ushort4(vcol[0], vcol[1], vcol[2], vcol[3]);
    *(ushort4*)&Bs[ev * 40 + s8 + 4] = make_ushort4(vcol[4], vcol[5], vcol[6], vcol[7]);
    __syncthreads();
    f16x8 af[4], bfr[2];
#pragma unroll
    for (int i = 0; i < 4; ++i) af[i] = *(const f16x8*)&As[(wm * 64 + i * 16 + l16) * 32 + quad * 8];
#pragma unroll
    for (int j = 0; j < 2; ++j) bfr[j] = *(const f16x8*)&Bs[(wn * 32 + j * 16 + l16) * 40 + quad * 8];
#pragma unroll
    for (int i = 0; i < 4; ++i)
#pragma unroll
      for (int j = 0; j < 2; ++j) acc[i][j] = MFMA_F16(af[i], bfr[j], acc[i][j]);
  }
#pragma unroll
  for (int i = 0; i < 4; ++i)
#pragma unroll
    for (int j = 0; j < 2; ++j)
#pragma unroll
      for (int r = 0; r < 4; ++r) {
        int q = m0 + wm * 64 + i * 16 + quad * 4 + r;
        int e = wn * 32 + j * 16 + l16;
        ctx[(size_t)(b * 1024 + q) * 768 + h * 64 + e] = f2h(acc[i][j][r]);
      }
}

// ---------------- K5: out = ctx @ Wp^T + bp ----------------
__global__ __launch_bounds__(256) void k_oproj(const u16* __restrict__ A,
                                               const u16* __restrict__ Bm,
                                               const float* __restrict__ bp,
                                               float* __restrict__ out) {
  __shared__ u16 As[4096];
  __shared__ u16 Bs[4096];
  const int t = threadIdx.x, lane = t & 63, wave = t >> 6;
  const int wm = wave >> 1, wn = wave & 1;
  const int quad = lane >> 4, l16 = lane & 15;
  const int m0 = blockIdx.y * 128, n0 = blockIdx.x * 128;
  const int srow = t >> 2, sch = (t & 3) * 8;
  f32x4 acc[4][4];
#pragma unroll
  for (int i = 0; i < 4; ++i)
#pragma unroll
    for (int j = 0; j < 4; ++j) acc[i][j] = (f32x4){0.f, 0.f, 0.f, 0.f};
  for (int k0 = 0; k0 < 768; k0 += 32) {
    __syncthreads();
    const u16* ga = A + (size_t)(m0 + srow) * 768 + k0 + sch;
    const u16* gb = Bm + (size_t)(n0 + srow) * 768 + k0 + sch;
    async16(ga, &As[t * 8]);
    async16(ga + (size_t)64 * 768, &As[2048 + t * 8]);
    async16(gb, &Bs[t * 8]);
    async16(gb + (size_t)64 * 768, &Bs[2048 + t * 8]);
    __syncthreads();
    f16x8 af[4], bfr[4];
#pragma unroll
    for (int i = 0; i < 4; ++i) af[i] = *(const f16x8*)&As[(wm * 64 + i * 16 + l16) * 32 + quad * 8];
#pragma unroll
    for (int j = 0; j < 4; ++j) bfr[j] = *(const f16x8*)&Bs[(wn * 64 + j * 16 + l16) * 32 + quad * 8];
#pragma unroll
    for (int i = 0; i < 4; ++i)
#pragma unroll
      for (int j = 0; j < 4; ++j) acc[i][j] = MFMA_F16(af[i], bfr[j], acc[i][j]);
  }
#pragma unroll
  for (int i = 0; i < 4; ++i)
#pragma unroll
    for (int j = 0; j < 4; ++j)
#pragma unroll
      for (int r = 0; r < 4; ++r) {
        const int row = m0 + wm * 64 + i * 16 + quad * 4 + r;
        const int col = n0 + wn * 64 + j * 16 + l16;
        out[(size_t)row * 768 + col] = acc[i][j][r] + bp[col];
      }
}

extern "C" void kernel_launch(void* const* d_in, const int* in_sizes, int n_in,
                              void* d_out, int out_size, void* d_ws, size_t ws_size,
                              hipStream_t stream) {
  const float* x    = (const float*)d_in[0];
  const float* Wqkv = (const float*)d_in[1];
  const float* Wl   = (const float*)d_in[2];
  const float* bl   = (const float*)d_in[3];
  const float* Ww   = (const float*)d_in[4];
  const float* bw   = (const float*)d_in[5];
  const float* Wp   = (const float*)d_in[6];
  const float* bp   = (const float*)d_in[7];
  float* out = (float*)d_out;

  char* ws = (char*)d_ws;
  u16* scbuf   = (u16*)(ws + 0);               // 100,663,296 B, P2 [b][q][g][k]
  u16* qkf     = (u16*)(ws + 100663296ull);    //  12,582,912 B
  u16* vbuf    = (u16*)(ws + 113246208ull);    //   6,291,456 B
  u16* ctx     = (u16*)(ws + 119537664ull);    //   6,291,456 B
  float* dpart = (float*)(ws + 119537664ull);  //   6,291,456 B (dead before k_pv writes ctx)
  u16* x_h     = (u16*)(ws + 125829120ull);    //   6,291,456 B
  float* dfinal= (float*)(ws + 125829120ull);  //     196,608 B (x_h dead after k_qkv)
  u16* wq_h    = (u16*)(ws + 132120576ull);    //   3,538,944 B
  u16* wp_h    = (u16*)(ws + 135659520ull);    //   1,179,648 B

  hipLaunchKernelGGL(k_prep, dim3(5376), dim3(256), 0, stream,
                     x, Wqkv, Wp, x_h, wq_h, wp_h);
  hipLaunchKernelGGL(k_qkv, dim3(576), dim3(256), 0, stream, x_h, wq_h, qkf, vbuf);
  hipLaunchKernelGGL(k_qkmix_sum, dim3(32, 16, 4), dim3(256), 0, stream, qkf, Wl, bl, dpart);
  hipLaunchKernelGGL(k_dsum, dim3(192), dim3(256), 0, stream, dpart, dfinal);
  hipLaunchKernelGGL(k_qkmix_store, dim3(32, 16, 4), dim3(256), 0, stream,
                     qkf, Wl, bl, Ww, bw, dfinal, scbuf);
  hipLaunchKernelGGL(k_pv, dim3(8, 48), dim3(256), 0, stream, scbuf, vbuf, ctx);
  hipLaunchKernelGGL(k_oproj, dim3(6, 32), dim3(256), 0, stream, ctx, wp_h, bp, out);
}

// Round 5
// 247.591 us; speedup vs baseline: 1.5339x; 1.5339x over previous
//
#include <hip/hip_runtime.h>
#include <math.h>

// B=4, S=1024, D=768, H=12, E=64, 3D=2304
// Workspace layout (bytes), total ~137 MB:
//   scbuf fp16 scores -> fp16 probs in place : 100,663,296 @ 0
//     layout [b][q][h][k] head-minor (head stride 1024 u16, q stride 12*1024)
//   qkf  fp16 [4096][1536] (Q,K)  : 12,582,912 @ 100,663,296
//   vbuf fp16 [4096][768]  (V)    :  6,291,456 @ 113,246,208
//   ctx  fp16 [4096][768]         :  6,291,456 @ 119,537,664
//   x_h  fp16 :  6,291,456 @ 125,829,120
//   wq_h fp16 :  3,538,944 @ 132,120,576
//   wp_h fp16 :  1,179,648 @ 135,659,520
//
// R5 == R4 with the MFMA16 intrinsic name fixed (gfx950 spelling is
// __builtin_amdgcn_mfma_f32_16x16x16f16 — no underscore before f16).
// k_mix on MFMA 16x16x16:
//  - mix1: C1[g][k] = MFMA(Wl-frag, S-frag) + (bl-16); S staged linear+pad8
//  - E = exp(C1) kept in 64 f32 regs; softmax sums via shfl+LDS (2 barriers)
//  - P = E*dinv packed fp16 == mix2's B-operand layout in-register (C rows
//    quad*4+r match B kdim slots quad*4+i) -> zero shuffle between mixes
//  - mix2: C2 = MFMA(Ww-frag, P) + bw -> fp16 stores

typedef _Float16 f16;
typedef __attribute__((ext_vector_type(8))) _Float16 f16x8;
typedef __attribute__((ext_vector_type(4))) _Float16 f16x4;
typedef __attribute__((ext_vector_type(2))) _Float16 f16x2;
typedef __attribute__((ext_vector_type(4))) float f32x4;
typedef __attribute__((ext_vector_type(2))) float f32x2;
typedef __attribute__((ext_vector_type(2))) unsigned u32x2;
typedef unsigned short u16;

__device__ __forceinline__ u16 f2h(float f) {      // RTN convert
  f16 h = (f16)f;
  return __builtin_bit_cast(u16, h);
}
__device__ __forceinline__ unsigned pk2h(float a, float b) {
  return __builtin_bit_cast(unsigned, __builtin_amdgcn_cvt_pkrtz(a, b));
}

__device__ __forceinline__ void async16(const void* g, void* l) {
  __builtin_amdgcn_global_load_lds(
      (const __attribute__((address_space(1))) unsigned int*)g,
      (__attribute__((address_space(3))) unsigned int*)l, 16, 0, 0);
}

#define MFMA_F16(a, b, c) __builtin_amdgcn_mfma_f32_16x16x32_f16((a), (b), (c), 0, 0, 0)
#define MFMA16(a, b, c) __builtin_amdgcn_mfma_f32_16x16x16f16((a), (b), (c), 0, 0, 0)

// ---------------- prep: cast x, Wqkv, Wp to fp16 ----------------
__global__ __launch_bounds__(256) void k_prep(const float* __restrict__ x,
                                              const float* __restrict__ Wqkv,
                                              const float* __restrict__ Wp,
                                              u16* __restrict__ xh,
                                              u16* __restrict__ wh,
                                              u16* __restrict__ wph) {
  const int blk = blockIdx.x, t = threadIdx.x;
  if (blk < 3072) {
    int i = blk * 256 + t;
    float4 v = ((const float4*)x)[i];
    ((ushort4*)xh)[i] = make_ushort4(f2h(v.x), f2h(v.y), f2h(v.z), f2h(v.w));
  } else if (blk < 4800) {
    int i = (blk - 3072) * 256 + t;
    float4 v = ((const float4*)Wqkv)[i];
    ((ushort4*)wh)[i] = make_ushort4(f2h(v.x), f2h(v.y), f2h(v.z), f2h(v.w));
  } else {
    int i = (blk - 4800) * 256 + t;
    float4 v = ((const float4*)Wp)[i];
    ((ushort4*)wph)[i] = make_ushort4(f2h(v.x), f2h(v.y), f2h(v.z), f2h(v.w));
  }
}

// ---------------- K1: qkv = x @ Wqkv^T, fp16 single-MFMA ----------------
__global__ __launch_bounds__(256) void k_qkv(const u16* __restrict__ Axh,
                                             const u16* __restrict__ Bwh,
                                             u16* __restrict__ qkf,
                                             u16* __restrict__ vbuf) {
  __shared__ u16 smem[16384];
  u16* As = smem;
  u16* Bs = smem + 4096;
  const int t = threadIdx.x, lane = t & 63, wave = t >> 6;
  const int wm = wave >> 1, wn = wave & 1;
  const int quad = lane >> 4, l16 = lane & 15;
  const int pid = blockIdx.x;
  const int group = pid / 144;
  const int rem = pid - group * 144;
  const int m0 = (group * 8 + (rem & 7)) * 128;
  const int n0 = (rem >> 3) * 128;
  const bool vblk = (n0 >= 1536);
  const int srow = t >> 2, sch = (t & 3) * 8;
  f32x4 acc[4][4];
#pragma unroll
  for (int i = 0; i < 4; ++i)
#pragma unroll
    for (int j = 0; j < 4; ++j) acc[i][j] = (f32x4){0.f, 0.f, 0.f, 0.f};
  for (int k0 = 0; k0 < 768; k0 += 32) {
    const size_t ga = (size_t)(m0 + srow) * 768 + k0 + sch;
    const size_t gb = (size_t)(n0 + srow) * 768 + k0 + sch;
    __syncthreads();
    async16(Axh + ga, &As[t * 8]);
    async16(Axh + ga + (size_t)64 * 768, &As[2048 + t * 8]);
    async16(Bwh + gb, &Bs[t * 8]);
    async16(Bwh + gb + (size_t)64 * 768, &Bs[2048 + t * 8]);
    __syncthreads();
    f16x8 af[4], bfr[4];
#pragma unroll
    for (int i = 0; i < 4; ++i) af[i] = *(const f16x8*)&As[(wm * 64 + i * 16 + l16) * 32 + quad * 8];
#pragma unroll
    for (int j = 0; j < 4; ++j) bfr[j] = *(const f16x8*)&Bs[(wn * 64 + j * 16 + l16) * 32 + quad * 8];
#pragma unroll
    for (int i = 0; i < 4; ++i)
#pragma unroll
      for (int j = 0; j < 4; ++j) acc[i][j] = MFMA_F16(af[i], bfr[j], acc[i][j]);
  }
  __syncthreads();
  u16* T = smem;
#pragma unroll
  for (int i = 0; i < 4; ++i)
#pragma unroll
    for (int j = 0; j < 4; ++j)
#pragma unroll
      for (int r = 0; r < 4; ++r) {
        const int row = wm * 64 + i * 16 + quad * 4 + r;
        const int col = wn * 64 + j * 16 + l16;
        T[row * 128 + (col ^ ((row & 7) << 4))] = f2h(acc[i][j][r]);
      }
  __syncthreads();
  const int row = t >> 1, halfc = (t & 1) * 64;
  const int sw = (row & 7) << 4;
  u16* dst = vblk ? (vbuf + (size_t)(m0 + row) * 768 + (n0 - 1536) + halfc)
                  : (qkf + (size_t)(m0 + row) * 1536 + n0 + halfc);
#pragma unroll
  for (int c = 0; c < 64; c += 8)
    *(uint4*)(dst + c) = *(const uint4*)&T[row * 128 + ((halfc + c) ^ sw)];
}

// ---------------- K2: scores(fp16) = Q @ K^T per (b,h) ----------------
// Output head-minor: scbuf[((b*1024+q)*12 + h)*1024 + k]
__global__ __launch_bounds__(256) void k_qk(const u16* __restrict__ qkf,
                                            u16* __restrict__ scbuf) {
  __shared__ u16 smem[4][4096];
  u16* As = smem[0]; u16* Bs = smem[1];
  const int t = threadIdx.x, lane = t & 63, wave = t >> 6;
  const int wm = wave >> 1, wn = wave & 1;
  const int quad = lane >> 4, l16 = lane & 15;
  const int bh = blockIdx.z, b = bh / 12, h = bh % 12;
  const int m0 = blockIdx.y * 128, n0 = blockIdx.x * 128;
  const int srow = t >> 2, sch = (t & 3) * 8;
  f32x4 acc[4][4];
#pragma unroll
  for (int i = 0; i < 4; ++i)
#pragma unroll
    for (int j = 0; j < 4; ++j) acc[i][j] = (f32x4){0.f, 0.f, 0.f, 0.f};
  for (int k0 = 0; k0 < 64; k0 += 32) {
    const size_t ga = (size_t)(b * 1024 + m0 + srow) * 1536 + h * 64 + k0 + sch;
    const size_t gb = (size_t)(b * 1024 + n0 + srow) * 1536 + 768 + h * 64 + k0 + sch;
    __syncthreads();
    async16(qkf + ga, &As[t * 8]);
    async16(qkf + ga + (size_t)64 * 1536, &As[2048 + t * 8]);
    async16(qkf + gb, &Bs[t * 8]);
    async16(qkf + gb + (size_t)64 * 1536, &Bs[2048 + t * 8]);
    __syncthreads();
    f16x8 af[4], bfr[4];
#pragma unroll
    for (int i = 0; i < 4; ++i) af[i] = *(const f16x8*)&As[(wm * 64 + i * 16 + l16) * 32 + quad * 8];
#pragma unroll
    for (int j = 0; j < 4; ++j) bfr[j] = *(const f16x8*)&Bs[(wn * 64 + j * 16 + l16) * 32 + quad * 8];
#pragma unroll
    for (int i = 0; i < 4; ++i)
#pragma unroll
      for (int j = 0; j < 4; ++j) acc[i][j] = MFMA_F16(af[i], bfr[j], acc[i][j]);
  }
  __syncthreads();
  u16* T = &smem[0][0];
#pragma unroll
  for (int i = 0; i < 4; ++i)
#pragma unroll
    for (int j = 0; j < 4; ++j)
#pragma unroll
      for (int r = 0; r < 4; ++r) {
        const int row = wm * 64 + i * 16 + quad * 4 + r;
        const int col = wn * 64 + j * 16 + l16;
        T[row * 128 + (col ^ ((row & 7) << 4))] = f2h(acc[i][j][r]);
      }
  __syncthreads();
  const int row = t >> 1, halfc = (t & 1) * 64;
  const int sw = (row & 7) << 4;
  u16* dst = scbuf + ((size_t)(b * 1024 + m0 + row) * 12 + h) * 1024 + n0 + halfc;
#pragma unroll
  for (int c = 0; c < 64; c += 8)
    *(uint4*)(dst + c) = *(const uint4*)&T[row * 128 + ((halfc + c) ^ sw)];
}

// ---------------- K3: mix1 -> softmax -> mix2 on MFMA 16x16x16, in place ----------------
// One block per (b,q). Wave w owns k-tiles w*16..w*16+15.
// Fragment map (16x16x16 f16): A[m=l16][kd=quad*4+i], B[kd=quad*4+i][n=l16],
// C[m=quad*4+r][n=l16]. C-rows == B-kdim slots -> mix1 output feeds mix2 B
// operand in-register after exp/normalize (no cross-lane movement).
__global__ __launch_bounds__(256) void k_mix(u16* __restrict__ scbuf,
                                             const float* __restrict__ Wl,
                                             const float* __restrict__ bl,
                                             const float* __restrict__ Ww,
                                             const float* __restrict__ bw) {
  __shared__ u16 S[12 * 1032];          // rows padded +8 u16 (stride 1032): <=2-way banks
  __shared__ float red[4][16];
  const int t = threadIdx.x, lane = t & 63, wave = t >> 6;
  const int quad = lane >> 4, l16 = lane & 15;
  const int bq = blockIdx.x, b = bq >> 10, q = bq & 1023;
  const size_t qslab = (size_t)(b * 1024 + q) * 12288;   // 12*1024 u16
  // stage S[12][1024] (+pad) : 1548 chunks of 16B, lane-linear LDS dest
#pragma unroll
  for (int i = 0; i < 7; ++i) {
    const int ci = i * 256 + t;
    if (ci < 1548) {
      const int row = ci / 129, c = ci - row * 129;
      async16(scbuf + qslab + row * 1024 + c * 8, &S[ci * 8]);  // c==128 pad: never read
    }
  }
  // constant fragments (h>=12 and g>=12 zeroed -> no NaN paths)
  const bool act = (quad < 3);
  f16x4 Awl = (f16x4){0, 0, 0, 0}, Aww = (f16x4){0, 0, 0, 0};
  if (act && l16 < 12) {
    const float4 wl4 = *(const float4*)&Wl[l16 * 12 + quad * 4];
    const float4 ww4 = *(const float4*)&Ww[l16 * 12 + quad * 4];
    Awl[0] = (f16)wl4.x; Awl[1] = (f16)wl4.y; Awl[2] = (f16)wl4.z; Awl[3] = (f16)wl4.w;
    Aww[0] = (f16)ww4.x; Aww[1] = (f16)ww4.y; Aww[2] = (f16)ww4.z; Aww[3] = (f16)ww4.w;
  }
  float blv[4], bwv[4];
#pragma unroll
  for (int r = 0; r < 4; ++r) {
    blv[r] = act ? bl[quad * 4 + r] - 16.f : 0.f;   // constant-shift softmax
    bwv[r] = act ? bw[quad * 4 + r] : 0.f;
  }
  int roff[4];
#pragma unroll
  for (int j = 0; j < 4; ++j) roff[j] = (quad * 4 + j) * 1032 + l16;
  __syncthreads();
  // pass 1: mix1 MFMA + exp; E kept in f32 registers; accumulate row sums
  float Ev[16][4];
  float a0 = 0.f, a1 = 0.f, a2 = 0.f, a3 = 0.f;
#pragma unroll
  for (int i = 0; i < 16; ++i) {
    const int kb = (wave * 16 + i) * 16;
    f16x4 B1 = (f16x4){0, 0, 0, 0};
    if (act) {
#pragma unroll
      for (int j = 0; j < 4; ++j) B1[j] = __builtin_bit_cast(f16, S[roff[j] + kb]);
    }
    f32x4 c1 = (f32x4){blv[0], blv[1], blv[2], blv[3]};
    c1 = MFMA16(Awl, B1, c1);
    const float e0 = __expf(c1[0]), e1 = __expf(c1[1]);
    const float e2 = __expf(c1[2]), e3 = __expf(c1[3]);
    Ev[i][0] = e0; Ev[i][1] = e1; Ev[i][2] = e2; Ev[i][3] = e3;
    a0 += e0; a1 += e1; a2 += e2; a3 += e3;
  }
  // reduce over the 16 k-columns held by l16 lanes
#pragma unroll
  for (int m = 1; m <= 8; m <<= 1) {
    a0 += __shfl_xor(a0, m); a1 += __shfl_xor(a1, m);
    a2 += __shfl_xor(a2, m); a3 += __shfl_xor(a3, m);
  }
  if (l16 == 0) {
    red[wave][quad * 4 + 0] = a0; red[wave][quad * 4 + 1] = a1;
    red[wave][quad * 4 + 2] = a2; red[wave][quad * 4 + 3] = a3;
  }
  __syncthreads();
  float dinv[4];
#pragma unroll
  for (int r = 0; r < 4; ++r) {
    const int g = quad * 4 + r;
    dinv[r] = 1.0f / (red[0][g] + red[1][g] + red[2][g] + red[3][g]);
  }
  // pass 2: P = E*dinv (fp16, in [0,1]) -> mix2 MFMA -> fp16 stores
  u16* const outp = scbuf + qslab + (size_t)quad * 4096 + l16;   // + r*1024 + kb
#pragma unroll
  for (int i = 0; i < 16; ++i) {
    const int kb = (wave * 16 + i) * 16;
    const unsigned lo = pk2h(Ev[i][0] * dinv[0], Ev[i][1] * dinv[1]);
    const unsigned hi = pk2h(Ev[i][2] * dinv[2], Ev[i][3] * dinv[3]);
    u32x2 pw = {lo, hi};
    const f16x4 Pf = __builtin_bit_cast(f16x4, pw);
    f32x4 c2 = (f32x4){bwv[0], bwv[1], bwv[2], bwv[3]};
    c2 = MFMA16(Aww, Pf, c2);
    if (act) {
#pragma unroll
      for (int r = 0; r < 4; ++r) outp[r * 1024 + kb] = f2h(c2[r]);
    }
  }
}

// ---------------- K4: ctx = P2(fp16) @ V(fp16) per (b,h); V transposed in-LDS ----------------
__global__ __launch_bounds__(256) void k_pv(const u16* __restrict__ probs,
                                            const u16* __restrict__ vbuf,
                                            u16* __restrict__ ctx) {
  __shared__ u16 As[4096];      // 128x32 P tile
  __shared__ u16 Bs[64 * 40];   // V^T tile: [e][s-chunk 32], row stride 40
  const int t = threadIdx.x, lane = t & 63, wave = t >> 6;
  const int wm = wave >> 1, wn = wave & 1;
  const int quad = lane >> 4, l16 = lane & 15;
  const int bh = blockIdx.y, b = bh / 12, h = bh % 12;
  const int m0 = blockIdx.x * 128;
  const int srow = t >> 2, sch = (t & 3) * 8;
  const int ev = t & 63, s8 = (t >> 6) * 8;
  f32x4 acc[4][2];
#pragma unroll
  for (int i = 0; i < 4; ++i)
#pragma unroll
    for (int j = 0; j < 2; ++j) acc[i][j] = (f32x4){0.f, 0.f, 0.f, 0.f};
  for (int k0 = 0; k0 < 1024; k0 += 32) {
    const u16* vp = vbuf + (size_t)(b * 1024 + k0 + s8) * 768 + h * 64 + ev;
    u16 vcol[8];
#pragma unroll
    for (int i = 0; i < 8; ++i) vcol[i] = vp[(size_t)i * 768];
    __syncthreads();
    const u16* ga = probs + ((size_t)(b * 1024 + m0 + srow) * 12 + h) * 1024 + k0 + sch;
    async16(ga, &As[t * 8]);
    async16(ga + (size_t)64 * 12 * 1024, &As[2048 + t * 8]);
    *(ushort4*)&Bs[ev * 40 + s8] = make_ushort4(vcol[0], vcol[1], vcol[2], vcol[3]);
    *(ushort4*)&Bs[ev * 40 + s8 + 4] = make_ushort4(vcol[4], vcol[5], vcol[6], vcol[7]);
    __syncthreads();
    f16x8 af[4], bfr[2];
#pragma unroll
    for (int i = 0; i < 4; ++i) af[i] = *(const f16x8*)&As[(wm * 64 + i * 16 + l16) * 32 + quad * 8];
#pragma unroll
    for (int j = 0; j < 2; ++j) bfr[j] = *(const f16x8*)&Bs[(wn * 32 + j * 16 + l16) * 40 + quad * 8];
#pragma unroll
    for (int i = 0; i < 4; ++i)
#pragma unroll
      for (int j = 0; j < 2; ++j) acc[i][j] = MFMA_F16(af[i], bfr[j], acc[i][j]);
  }
#pragma unroll
  for (int i = 0; i < 4; ++i)
#pragma unroll
    for (int j = 0; j < 2; ++j)
#pragma unroll
      for (int r = 0; r < 4; ++r) {
        int q = m0 + wm * 64 + i * 16 + quad * 4 + r;
        int e = wn * 32 + j * 16 + l16;
        ctx[(size_t)(b * 1024 + q) * 768 + h * 64 + e] = f2h(acc[i][j][r]);
      }
}

// ---------------- K5: out = ctx @ Wp^T + bp (fp16 MFMA, fp32 out) ----------------
__global__ __launch_bounds__(256) void k_oproj(const u16* __restrict__ A,
                                               const u16* __restrict__ Bm,
                                               const float* __restrict__ bp,
                                               float* __restrict__ out) {
  __shared__ u16 As[4096];
  __shared__ u16 Bs[4096];
  const int t = threadIdx.x, lane = t & 63, wave = t >> 6;
  const int wm = wave >> 1, wn = wave & 1;
  const int quad = lane >> 4, l16 = lane & 15;
  const int m0 = blockIdx.y * 128, n0 = blockIdx.x * 128;
  const int srow = t >> 2, sch = (t & 3) * 8;
  f32x4 acc[4][4];
#pragma unroll
  for (int i = 0; i < 4; ++i)
#pragma unroll
    for (int j = 0; j < 4; ++j) acc[i][j] = (f32x4){0.f, 0.f, 0.f, 0.f};
  for (int k0 = 0; k0 < 768; k0 += 32) {
    __syncthreads();
    const u16* ga = A + (size_t)(m0 + srow) * 768 + k0 + sch;
    const u16* gb = Bm + (size_t)(n0 + srow) * 768 + k0 + sch;
    async16(ga, &As[t * 8]);
    async16(ga + (size_t)64 * 768, &As[2048 + t * 8]);
    async16(gb, &Bs[t * 8]);
    async16(gb + (size_t)64 * 768, &Bs[2048 + t * 8]);
    __syncthreads();
    f16x8 af[4], bfr[4];
#pragma unroll
    for (int i = 0; i < 4; ++i) af[i] = *(const f16x8*)&As[(wm * 64 + i * 16 + l16) * 32 + quad * 8];
#pragma unroll
    for (int j = 0; j < 4; ++j) bfr[j] = *(const f16x8*)&Bs[(wn * 64 + j * 16 + l16) * 32 + quad * 8];
#pragma unroll
    for (int i = 0; i < 4; ++i)
#pragma unroll
      for (int j = 0; j < 4; ++j) acc[i][j] = MFMA_F16(af[i], bfr[j], acc[i][j]);
  }
#pragma unroll
  for (int i = 0; i < 4; ++i)
#pragma unroll
    for (int j = 0; j < 4; ++j)
#pragma unroll
      for (int r = 0; r < 4; ++r) {
        const int row = m0 + wm * 64 + i * 16 + quad * 4 + r;
        const int col = n0 + wn * 64 + j * 16 + l16;
        out[(size_t)row * 768 + col] = acc[i][j][r] + bp[col];
      }
}

extern "C" void kernel_launch(void* const* d_in, const int* in_sizes, int n_in,
                              void* d_out, int out_size, void* d_ws, size_t ws_size,
                              hipStream_t stream) {
  const float* x    = (const float*)d_in[0];
  const float* Wqkv = (const float*)d_in[1];
  const float* Wl   = (const float*)d_in[2];
  const float* bl   = (const float*)d_in[3];
  const float* Ww   = (const float*)d_in[4];
  const float* bw   = (const float*)d_in[5];
  const float* Wp   = (const float*)d_in[6];
  const float* bp   = (const float*)d_in[7];
  float* out = (float*)d_out;

  char* ws = (char*)d_ws;
  u16* scbuf = (u16*)(ws + 0);               // 100,663,296 B, [b][q][h][k]
  u16* qkf   = (u16*)(ws + 100663296ull);    //  12,582,912 B
  u16* vbuf  = (u16*)(ws + 113246208ull);    //   6,291,456 B
  u16* ctx   = (u16*)(ws + 119537664ull);    //   6,291,456 B
  u16* x_h   = (u16*)(ws + 125829120ull);    //   6,291,456 B
  u16* wq_h  = (u16*)(ws + 132120576ull);    //   3,538,944 B
  u16* wp_h  = (u16*)(ws + 135659520ull);    //   1,179,648 B

  hipLaunchKernelGGL(k_prep, dim3(5376), dim3(256), 0, stream,
                     x, Wqkv, Wp, x_h, wq_h, wp_h);
  hipLaunchKernelGGL(k_qkv,  dim3(576),      dim3(256), 0, stream, x_h, wq_h, qkf, vbuf);
  hipLaunchKernelGGL(k_qk,   dim3(8, 8, 48), dim3(256), 0, stream, qkf, scbuf);
  hipLaunchKernelGGL(k_mix,  dim3(4096),     dim3(256), 0, stream, scbuf, Wl, bl, Ww, bw);
  hipLaunchKernelGGL(k_pv,   dim3(8, 48),    dim3(256), 0, stream, scbuf, vbuf, ctx);
  hipLaunchKernelGGL(k_oproj, dim3(6, 32),   dim3(256), 0, stream, ctx, wp_h, bp, out);
}

// Round 6
// 241.522 us; speedup vs baseline: 1.5724x; 1.0251x over previous
//
#include <hip/hip_runtime.h>
#include <math.h>

// B=4, S=1024, D=768, H=12, E=64, 3D=2304
// Workspace layout (bytes), total ~137 MB:
//   scbuf fp16 scores -> fp16 probs in place : 100,663,296 @ 0
//     layout [b][q][h][k] head-minor (head stride 1024 u16, q stride 12*1024)
//   qkf  fp16 [4096][1536] (Q,K)  : 12,582,912 @ 100,663,296
//   vbuf fp16 [4096][768]  (V)    :  6,291,456 @ 113,246,208
//   ctx  fp16 [4096][768]         :  6,291,456 @ 119,537,664
//   x_h  fp16 :  6,291,456 @ 125,829,120
//   wq_h fp16 :  3,538,944 @ 132,120,576
//   wp_h fp16 :  1,179,648 @ 135,659,520
//
// R6: k_qk rebuilt (only kernel changed vs R5):
//  - ONE staging phase (Q[128][64]+K[128][64], 32KB, 8 async16/thread),
//    3 barriers/block total (was 6)
//  - chunk-XOR both-sides swizzle on staged tiles -> conflict-optimal
//    ds_read_b128 fragment reads
//  - repack T stride 136 u16 (68 dw, 4-bank shift/row): 2-way-free writes,
//    optimal uint4 reads, no XOR

typedef _Float16 f16;
typedef __attribute__((ext_vector_type(8))) _Float16 f16x8;
typedef __attribute__((ext_vector_type(4))) _Float16 f16x4;
typedef __attribute__((ext_vector_type(2))) _Float16 f16x2;
typedef __attribute__((ext_vector_type(4))) float f32x4;
typedef __attribute__((ext_vector_type(2))) float f32x2;
typedef __attribute__((ext_vector_type(2))) unsigned u32x2;
typedef unsigned short u16;

__device__ __forceinline__ u16 f2h(float f) {      // RTN convert
  f16 h = (f16)f;
  return __builtin_bit_cast(u16, h);
}
__device__ __forceinline__ unsigned pk2h(float a, float b) {
  return __builtin_bit_cast(unsigned, __builtin_amdgcn_cvt_pkrtz(a, b));
}

__device__ __forceinline__ void async16(const void* g, void* l) {
  __builtin_amdgcn_global_load_lds(
      (const __attribute__((address_space(1))) unsigned int*)g,
      (__attribute__((address_space(3))) unsigned int*)l, 16, 0, 0);
}

#define MFMA_F16(a, b, c) __builtin_amdgcn_mfma_f32_16x16x32_f16((a), (b), (c), 0, 0, 0)
#define MFMA16(a, b, c) __builtin_amdgcn_mfma_f32_16x16x16f16((a), (b), (c), 0, 0, 0)

// ---------------- prep: cast x, Wqkv, Wp to fp16 ----------------
__global__ __launch_bounds__(256) void k_prep(const float* __restrict__ x,
                                              const float* __restrict__ Wqkv,
                                              const float* __restrict__ Wp,
                                              u16* __restrict__ xh,
                                              u16* __restrict__ wh,
                                              u16* __restrict__ wph) {
  const int blk = blockIdx.x, t = threadIdx.x;
  if (blk < 3072) {
    int i = blk * 256 + t;
    float4 v = ((const float4*)x)[i];
    ((ushort4*)xh)[i] = make_ushort4(f2h(v.x), f2h(v.y), f2h(v.z), f2h(v.w));
  } else if (blk < 4800) {
    int i = (blk - 3072) * 256 + t;
    float4 v = ((const float4*)Wqkv)[i];
    ((ushort4*)wh)[i] = make_ushort4(f2h(v.x), f2h(v.y), f2h(v.z), f2h(v.w));
  } else {
    int i = (blk - 4800) * 256 + t;
    float4 v = ((const float4*)Wp)[i];
    ((ushort4*)wph)[i] = make_ushort4(f2h(v.x), f2h(v.y), f2h(v.z), f2h(v.w));
  }
}

// ---------------- K1: qkv = x @ Wqkv^T, fp16 single-MFMA ----------------
__global__ __launch_bounds__(256) void k_qkv(const u16* __restrict__ Axh,
                                             const u16* __restrict__ Bwh,
                                             u16* __restrict__ qkf,
                                             u16* __restrict__ vbuf) {
  __shared__ u16 smem[16384];
  u16* As = smem;
  u16* Bs = smem + 4096;
  const int t = threadIdx.x, lane = t & 63, wave = t >> 6;
  const int wm = wave >> 1, wn = wave & 1;
  const int quad = lane >> 4, l16 = lane & 15;
  const int pid = blockIdx.x;
  const int group = pid / 144;
  const int rem = pid - group * 144;
  const int m0 = (group * 8 + (rem & 7)) * 128;
  const int n0 = (rem >> 3) * 128;
  const bool vblk = (n0 >= 1536);
  const int srow = t >> 2, sch = (t & 3) * 8;
  f32x4 acc[4][4];
#pragma unroll
  for (int i = 0; i < 4; ++i)
#pragma unroll
    for (int j = 0; j < 4; ++j) acc[i][j] = (f32x4){0.f, 0.f, 0.f, 0.f};
  for (int k0 = 0; k0 < 768; k0 += 32) {
    const size_t ga = (size_t)(m0 + srow) * 768 + k0 + sch;
    const size_t gb = (size_t)(n0 + srow) * 768 + k0 + sch;
    __syncthreads();
    async16(Axh + ga, &As[t * 8]);
    async16(Axh + ga + (size_t)64 * 768, &As[2048 + t * 8]);
    async16(Bwh + gb, &Bs[t * 8]);
    async16(Bwh + gb + (size_t)64 * 768, &Bs[2048 + t * 8]);
    __syncthreads();
    f16x8 af[4], bfr[4];
#pragma unroll
    for (int i = 0; i < 4; ++i) af[i] = *(const f16x8*)&As[(wm * 64 + i * 16 + l16) * 32 + quad * 8];
#pragma unroll
    for (int j = 0; j < 4; ++j) bfr[j] = *(const f16x8*)&Bs[(wn * 64 + j * 16 + l16) * 32 + quad * 8];
#pragma unroll
    for (int i = 0; i < 4; ++i)
#pragma unroll
      for (int j = 0; j < 4; ++j) acc[i][j] = MFMA_F16(af[i], bfr[j], acc[i][j]);
  }
  __syncthreads();
  u16* T = smem;
#pragma unroll
  for (int i = 0; i < 4; ++i)
#pragma unroll
    for (int j = 0; j < 4; ++j)
#pragma unroll
      for (int r = 0; r < 4; ++r) {
        const int row = wm * 64 + i * 16 + quad * 4 + r;
        const int col = wn * 64 + j * 16 + l16;
        T[row * 128 + (col ^ ((row & 7) << 4))] = f2h(acc[i][j][r]);
      }
  __syncthreads();
  const int row = t >> 1, halfc = (t & 1) * 64;
  const int sw = (row & 7) << 4;
  u16* dst = vblk ? (vbuf + (size_t)(m0 + row) * 768 + (n0 - 1536) + halfc)
                  : (qkf + (size_t)(m0 + row) * 1536 + n0 + halfc);
#pragma unroll
  for (int c = 0; c < 64; c += 8)
    *(uint4*)(dst + c) = *(const uint4*)&T[row * 128 + ((halfc + c) ^ sw)];
}

// ---------------- K2: scores(fp16) = Q @ K^T per (b,h) ----------------
// Output head-minor: scbuf[((b*1024+q)*12 + h)*1024 + k]
// R6: one staging phase, chunk-XOR swizzled tiles, stride-136 repack.
__global__ __launch_bounds__(256) void k_qk(const u16* __restrict__ qkf,
                                            u16* __restrict__ scbuf) {
  __shared__ u16 smem[17408];   // 34 KB: [0:8192)=Q, [8192:16384)=K; whole = T[128][136]
  u16* As = smem;
  u16* Bs = smem + 8192;
  const int t = threadIdx.x, lane = t & 63, wave = t >> 6;
  const int wm = wave >> 1, wn = wave & 1;
  const int quad = lane >> 4, l16 = lane & 15;
  const int bh = blockIdx.z, b = bh / 12, h = bh % 12;
  const int m0 = blockIdx.y * 128, n0 = blockIdx.x * 128;
  // single staging phase: As[row*64 + ch*8] holds Q feats (ch^(row&7))*8..
  // dest lane-linear (gload_lds constraint), source chunk pre-swizzled
#pragma unroll
  for (int i = 0; i < 4; ++i) {
    const int ci = i * 256 + t;
    const int row = ci >> 3, ch = ci & 7;
    const int chs = ch ^ (row & 7);
    async16(qkf + (size_t)(b * 1024 + m0 + row) * 1536 + h * 64 + chs * 8, &As[ci * 8]);
    async16(qkf + (size_t)(b * 1024 + n0 + row) * 1536 + 768 + h * 64 + chs * 8, &Bs[ci * 8]);
  }
  f32x4 acc[4][4];
#pragma unroll
  for (int i = 0; i < 4; ++i)
#pragma unroll
    for (int j = 0; j < 4; ++j) acc[i][j] = (f32x4){0.f, 0.f, 0.f, 0.f};
  __syncthreads();
  const int sx = l16 & 7;     // row&7 of every fragment row this lane touches
#pragma unroll
  for (int k0 = 0; k0 < 2; ++k0) {
    const int fch = ((k0 * 4 + quad) ^ sx) * 8;   // swizzled feat-chunk offset
    f16x8 af[4], bfr[4];
#pragma unroll
    for (int i = 0; i < 4; ++i) af[i] = *(const f16x8*)&As[(wm * 64 + i * 16 + l16) * 64 + fch];
#pragma unroll
    for (int j = 0; j < 4; ++j) bfr[j] = *(const f16x8*)&Bs[(wn * 64 + j * 16 + l16) * 64 + fch];
#pragma unroll
    for (int i = 0; i < 4; ++i)
#pragma unroll
      for (int j = 0; j < 4; ++j) acc[i][j] = MFMA_F16(af[i], bfr[j], acc[i][j]);
  }
  __syncthreads();
  u16* T = smem;   // [128][136]: 68 dw/row -> 4-bank shift per row, no XOR needed
#pragma unroll
  for (int i = 0; i < 4; ++i)
#pragma unroll
    for (int j = 0; j < 4; ++j)
#pragma unroll
      for (int r = 0; r < 4; ++r) {
        const int row = wm * 64 + i * 16 + quad * 4 + r;
        const int col = wn * 64 + j * 16 + l16;
        T[row * 136 + col] = f2h(acc[i][j][r]);
      }
  __syncthreads();
  const int row = t >> 1, halfc = (t & 1) * 64;
  u16* dst = scbuf + ((size_t)(b * 1024 + m0 + row) * 12 + h) * 1024 + n0 + halfc;
#pragma unroll
  for (int c = 0; c < 64; c += 8)
    *(uint4*)(dst + c) = *(const uint4*)&T[row * 136 + halfc + c];
}

// ---------------- K3: mix1 -> softmax -> mix2 on MFMA 16x16x16, in place ----------------
// One block per (b,q). Wave w owns k-tiles w*16..w*16+15.
// Fragment map (16x16x16 f16): A[m=l16][kd=quad*4+i], B[kd=quad*4+i][n=l16],
// C[m=quad*4+r][n=l16]. C-rows == B-kdim slots -> mix1 output feeds mix2 B
// operand in-register after exp/normalize (no cross-lane movement).
__global__ __launch_bounds__(256) void k_mix(u16* __restrict__ scbuf,
                                             const float* __restrict__ Wl,
                                             const float* __restrict__ bl,
                                             const float* __restrict__ Ww,
                                             const float* __restrict__ bw) {
  __shared__ u16 S[12 * 1032];          // rows padded +8 u16 (stride 1032): <=2-way banks
  __shared__ float red[4][16];
  const int t = threadIdx.x, lane = t & 63, wave = t >> 6;
  const int quad = lane >> 4, l16 = lane & 15;
  const int bq = blockIdx.x, b = bq >> 10, q = bq & 1023;
  const size_t qslab = (size_t)(b * 1024 + q) * 12288;   // 12*1024 u16
  // stage S[12][1024] (+pad) : 1548 chunks of 16B, lane-linear LDS dest
#pragma unroll
  for (int i = 0; i < 7; ++i) {
    const int ci = i * 256 + t;
    if (ci < 1548) {
      const int row = ci / 129, c = ci - row * 129;
      async16(scbuf + qslab + row * 1024 + c * 8, &S[ci * 8]);  // c==128 pad: never read
    }
  }
  // constant fragments (h>=12 and g>=12 zeroed -> no NaN paths)
  const bool act = (quad < 3);
  f16x4 Awl = (f16x4){0, 0, 0, 0}, Aww = (f16x4){0, 0, 0, 0};
  if (act && l16 < 12) {
    const float4 wl4 = *(const float4*)&Wl[l16 * 12 + quad * 4];
    const float4 ww4 = *(const float4*)&Ww[l16 * 12 + quad * 4];
    Awl[0] = (f16)wl4.x; Awl[1] = (f16)wl4.y; Awl[2] = (f16)wl4.z; Awl[3] = (f16)wl4.w;
    Aww[0] = (f16)ww4.x; Aww[1] = (f16)ww4.y; Aww[2] = (f16)ww4.z; Aww[3] = (f16)ww4.w;
  }
  float blv[4], bwv[4];
#pragma unroll
  for (int r = 0; r < 4; ++r) {
    blv[r] = act ? bl[quad * 4 + r] - 16.f : 0.f;   // constant-shift softmax
    bwv[r] = act ? bw[quad * 4 + r] : 0.f;
  }
  int roff[4];
#pragma unroll
  for (int j = 0; j < 4; ++j) roff[j] = (quad * 4 + j) * 1032 + l16;
  __syncthreads();
  // pass 1: mix1 MFMA + exp; E kept in f32 registers; accumulate row sums
  float Ev[16][4];
  float a0 = 0.f, a1 = 0.f, a2 = 0.f, a3 = 0.f;
#pragma unroll
  for (int i = 0; i < 16; ++i) {
    const int kb = (wave * 16 + i) * 16;
    f16x4 B1 = (f16x4){0, 0, 0, 0};
    if (act) {
#pragma unroll
      for (int j = 0; j < 4; ++j) B1[j] = __builtin_bit_cast(f16, S[roff[j] + kb]);
    }
    f32x4 c1 = (f32x4){blv[0], blv[1], blv[2], blv[3]};
    c1 = MFMA16(Awl, B1, c1);
    const float e0 = __expf(c1[0]), e1 = __expf(c1[1]);
    const float e2 = __expf(c1[2]), e3 = __expf(c1[3]);
    Ev[i][0] = e0; Ev[i][1] = e1; Ev[i][2] = e2; Ev[i][3] = e3;
    a0 += e0; a1 += e1; a2 += e2; a3 += e3;
  }
  // reduce over the 16 k-columns held by l16 lanes
#pragma unroll
  for (int m = 1; m <= 8; m <<= 1) {
    a0 += __shfl_xor(a0, m); a1 += __shfl_xor(a1, m);
    a2 += __shfl_xor(a2, m); a3 += __shfl_xor(a3, m);
  }
  if (l16 == 0) {
    red[wave][quad * 4 + 0] = a0; red[wave][quad * 4 + 1] = a1;
    red[wave][quad * 4 + 2] = a2; red[wave][quad * 4 + 3] = a3;
  }
  __syncthreads();
  float dinv[4];
#pragma unroll
  for (int r = 0; r < 4; ++r) {
    const int g = quad * 4 + r;
    dinv[r] = 1.0f / (red[0][g] + red[1][g] + red[2][g] + red[3][g]);
  }
  // pass 2: P = E*dinv (fp16, in [0,1]) -> mix2 MFMA -> fp16 stores
  u16* const outp = scbuf + qslab + (size_t)quad * 4096 + l16;   // + r*1024 + kb
#pragma unroll
  for (int i = 0; i < 16; ++i) {
    const int kb = (wave * 16 + i) * 16;
    const unsigned lo = pk2h(Ev[i][0] * dinv[0], Ev[i][1] * dinv[1]);
    const unsigned hi = pk2h(Ev[i][2] * dinv[2], Ev[i][3] * dinv[3]);
    u32x2 pw = {lo, hi};
    const f16x4 Pf = __builtin_bit_cast(f16x4, pw);
    f32x4 c2 = (f32x4){bwv[0], bwv[1], bwv[2], bwv[3]};
    c2 = MFMA16(Aww, Pf, c2);
    if (act) {
#pragma unroll
      for (int r = 0; r < 4; ++r) outp[r * 1024 + kb] = f2h(c2[r]);
    }
  }
}

// ---------------- K4: ctx = P2(fp16) @ V(fp16) per (b,h); V transposed in-LDS ----------------
__global__ __launch_bounds__(256) void k_pv(const u16* __restrict__ probs,
                                            const u16* __restrict__ vbuf,
                                            u16* __restrict__ ctx) {
  __shared__ u16 As[4096];      // 128x32 P tile
  __shared__ u16 Bs[64 * 40];   // V^T tile: [e][s-chunk 32], row stride 40
  const int t = threadIdx.x, lane = t & 63, wave = t >> 6;
  const int wm = wave >> 1, wn = wave & 1;
  const int quad = lane >> 4, l16 = lane & 15;
  const int bh = blockIdx.y, b = bh / 12, h = bh % 12;
  const int m0 = blockIdx.x * 128;
  const int srow = t >> 2, sch = (t & 3) * 8;
  const int ev = t & 63, s8 = (t >> 6) * 8;
  f32x4 acc[4][2];
#pragma unroll
  for (int i = 0; i < 4; ++i)
#pragma unroll
    for (int j = 0; j < 2; ++j) acc[i][j] = (f32x4){0.f, 0.f, 0.f, 0.f};
  for (int k0 = 0; k0 < 1024; k0 += 32) {
    const u16* vp = vbuf + (size_t)(b * 1024 + k0 + s8) * 768 + h * 64 + ev;
    u16 vcol[8];
#pragma unroll
    for (int i = 0; i < 8; ++i) vcol[i] = vp[(size_t)i * 768];
    __syncthreads();
    const u16* ga = probs + ((size_t)(b * 1024 + m0 + srow) * 12 + h) * 1024 + k0 + sch;
    async16(ga, &As[t * 8]);
    async16(ga + (size_t)64 * 12 * 1024, &As[2048 + t * 8]);
    *(ushort4*)&Bs[ev * 40 + s8] = make_ushort4(vcol[0], vcol[1], vcol[2], vcol[3]);
    *(ushort4*)&Bs[ev * 40 + s8 + 4] = make_ushort4(vcol[4], vcol[5], vcol[6], vcol[7]);
    __syncthreads();
    f16x8 af[4], bfr[2];
#pragma unroll
    for (int i = 0; i < 4; ++i) af[i] = *(const f16x8*)&As[(wm * 64 + i * 16 + l16) * 32 + quad * 8];
#pragma unroll
    for (int j = 0; j < 2; ++j) bfr[j] = *(const f16x8*)&Bs[(wn * 32 + j * 16 + l16) * 40 + quad * 8];
#pragma unroll
    for (int i = 0; i < 4; ++i)
#pragma unroll
      for (int j = 0; j < 2; ++j) acc[i][j] = MFMA_F16(af[i], bfr[j], acc[i][j]);
  }
#pragma unroll
  for (int i = 0; i < 4; ++i)
#pragma unroll
    for (int j = 0; j < 2; ++j)
#pragma unroll
      for (int r = 0; r < 4; ++r) {
        int q = m0 + wm * 64 + i * 16 + quad * 4 + r;
        int e = wn * 32 + j * 16 + l16;
        ctx[(size_t)(b * 1024 + q) * 768 + h * 64 + e] = f2h(acc[i][j][r]);
      }
}

// ---------------- K5: out = ctx @ Wp^T + bp (fp16 MFMA, fp32 out) ----------------
__global__ __launch_bounds__(256) void k_oproj(const u16* __restrict__ A,
                                               const u16* __restrict__ Bm,
                                               const float* __restrict__ bp,
                                               float* __restrict__ out) {
  __shared__ u16 As[4096];
  __shared__ u16 Bs[4096];
  const int t = threadIdx.x, lane = t & 63, wave = t >> 6;
  const int wm = wave >> 1, wn = wave & 1;
  const int quad = lane >> 4, l16 = lane & 15;
  const int m0 = blockIdx.y * 128, n0 = blockIdx.x * 128;
  const int srow = t >> 2, sch = (t & 3) * 8;
  f32x4 acc[4][4];
#pragma unroll
  for (int i = 0; i < 4; ++i)
#pragma unroll
    for (int j = 0; j < 4; ++j) acc[i][j] = (f32x4){0.f, 0.f, 0.f, 0.f};
  for (int k0 = 0; k0 < 768; k0 += 32) {
    __syncthreads();
    const u16* ga = A + (size_t)(m0 + srow) * 768 + k0 + sch;
    const u16* gb = Bm + (size_t)(n0 + srow) * 768 + k0 + sch;
    async16(ga, &As[t * 8]);
    async16(ga + (size_t)64 * 768, &As[2048 + t * 8]);
    async16(gb, &Bs[t * 8]);
    async16(gb + (size_t)64 * 768, &Bs[2048 + t * 8]);
    __syncthreads();
    f16x8 af[4], bfr[4];
#pragma unroll
    for (int i = 0; i < 4; ++i) af[i] = *(const f16x8*)&As[(wm * 64 + i * 16 + l16) * 32 + quad * 8];
#pragma unroll
    for (int j = 0; j < 4; ++j) bfr[j] = *(const f16x8*)&Bs[(wn * 64 + j * 16 + l16) * 32 + quad * 8];
#pragma unroll
    for (int i = 0; i < 4; ++i)
#pragma unroll
      for (int j = 0; j < 4; ++j) acc[i][j] = MFMA_F16(af[i], bfr[j], acc[i][j]);
  }
#pragma unroll
  for (int i = 0; i < 4; ++i)
#pragma unroll
    for (int j = 0; j < 4; ++j)
#pragma unroll
      for (int r = 0; r < 4; ++r) {
        const int row = m0 + wm * 64 + i * 16 + quad * 4 + r;
        const int col = n0 + wn * 64 + j * 16 + l16;
        out[(size_t)row * 768 + col] = acc[i][j][r] + bp[col];
      }
}

extern "C" void kernel_launch(void* const* d_in, const int* in_sizes, int n_in,
                              void* d_out, int out_size, void* d_ws, size_t ws_size,
                              hipStream_t stream) {
  const float* x    = (const float*)d_in[0];
  const float* Wqkv = (const float*)d_in[1];
  const float* Wl   = (const float*)d_in[2];
  const float* bl   = (const float*)d_in[3];
  const float* Ww   = (const float*)d_in[4];
  const float* bw   = (const float*)d_in[5];
  const float* Wp   = (const float*)d_in[6];
  const float* bp   = (const float*)d_in[7];
  float* out = (float*)d_out;

  char* ws = (char*)d_ws;
  u16* scbuf = (u16*)(ws + 0);               // 100,663,296 B, [b][q][h][k]
  u16* qkf   = (u16*)(ws + 100663296ull);    //  12,582,912 B
  u16* vbuf  = (u16*)(ws + 113246208ull);    //   6,291,456 B
  u16* ctx   = (u16*)(ws + 119537664ull);    //   6,291,456 B
  u16* x_h   = (u16*)(ws + 125829120ull);    //   6,291,456 B
  u16* wq_h  = (u16*)(ws + 132120576ull);    //   3,538,944 B
  u16* wp_h  = (u16*)(ws + 135659520ull);    //   1,179,648 B

  hipLaunchKernelGGL(k_prep, dim3(5376), dim3(256), 0, stream,
                     x, Wqkv, Wp, x_h, wq_h, wp_h);
  hipLaunchKernelGGL(k_qkv,  dim3(576),      dim3(256), 0, stream, x_h, wq_h, qkf, vbuf);
  hipLaunchKernelGGL(k_qk,   dim3(8, 8, 48), dim3(256), 0, stream, qkf, scbuf);
  hipLaunchKernelGGL(k_mix,  dim3(4096),     dim3(256), 0, stream, scbuf, Wl, bl, Ww, bw);
  hipLaunchKernelGGL(k_pv,   dim3(8, 48),    dim3(256), 0, stream, scbuf, vbuf, ctx);
  hipLaunchKernelGGL(k_oproj, dim3(6, 32),   dim3(256), 0, stream, ctx, wp_h, bp, out);
}